// Round 1
// baseline (508.230 us; speedup 1.0000x reference)
//
#include <hip/hip_runtime.h>
#include <math.h>

typedef unsigned short ushort_t;
typedef __attribute__((ext_vector_type(4))) float f32x4;
typedef __attribute__((ext_vector_type(8))) short short8;

#define MFMA16(a, b, c) __builtin_amdgcn_mfma_f32_16x16x32_bf16((a), (b), (c), 0, 0, 0)

// Problem dims (fixed)
constexpr int kB = 8;
constexpr int kC = 256;
constexpr int kM = 128;
constexpr int kN = 16384;

// ws layout (bytes, all 256-aligned). Total ~1.65 MB.
constexpr size_t kOffS    = 0;         // fp32 [8][128][256]
constexpr size_t kOffKsum = 1048576;   // fp32 [8][128]
constexpr size_t kOffXsum = 1052672;   // fp32 [8][256]
constexpr size_t kOffVsum = 1060864;   // fp32 [8][256]
constexpr size_t kOffWkb  = 1069056;   // bf16 [128][256]
constexpr size_t kOffWqb  = 1134592;   // bf16 [128][256]
constexpr size_t kOffMatT = 1200128;   // bf16 [8][256][128]  (matrix transposed)

__device__ __forceinline__ ushort_t f2bf(float f) {
  union { float f; unsigned u; } v; v.f = f;
  unsigned r = v.u + 0x7fffu + ((v.u >> 16) & 1u);
  return (ushort_t)(r >> 16);
}
__device__ __forceinline__ float bf2f(ushort_t h) {
  union { float f; unsigned u; } v; v.u = ((unsigned)h) << 16;
  return v.f;
}

// Barrier that drains LDS only (lgkmcnt(0)) and leaves global loads in
// flight — prefetched staging loads stay outstanding across the barrier.
__device__ __forceinline__ void sync_lds() {
  __atomic_signal_fence(__ATOMIC_SEQ_CST);
  __builtin_amdgcn_s_waitcnt(0xc07f);  // lgkmcnt(0), vmcnt/expcnt untouched
  __builtin_amdgcn_s_barrier();
  __atomic_signal_fence(__ATOMIC_SEQ_CST);
}

// ---------------- K0: zero accumulators + cast weights to bf16 ---------------
__global__ void k0_init(const float* __restrict__ Wq, const float* __restrict__ Wk,
                        float* __restrict__ ws_f, ushort_t* __restrict__ Wkb,
                        ushort_t* __restrict__ Wqb) {
  int i = blockIdx.x * 256 + threadIdx.x;  // 1024 x 256 = 262144 threads
  // zero S (262144 f) + Ksum (1024 f) + xsum (2048 f) contiguous
  for (int j = i; j < 265216; j += 262144) ws_f[j] = 0.0f;
  if (i < kM * kC) {
    Wkb[i] = f2bf(Wk[i]);
    Wqb[i] = f2bf(Wq[i]);
  }
}

// ---------------- K1: K-proj (MFMA) -> L2-norm -> S += Kn * x^T (MFMA) -------
// Pipeline-skewed: PhaseA_i = {prefetch i+1, norm+GEMM2 of tile i-1, stage i},
// PhaseB_i = {GEMM1 of tile i, red write}. 2 barriers/tile (was 3).
// grid (64, 8), block 512.
__global__ __launch_bounds__(512, 4)
void k1_acc(const float* __restrict__ x, const float* __restrict__ bk,
            const ushort_t* __restrict__ Wkb, float* __restrict__ S,
            float* __restrict__ Ksum, float* __restrict__ xsum) {
  // pitch 32 (no pad): analysis shows the b128 read pattern (row*64B + quad*16B)
  // and the uint2 write pattern are exactly conflict-free at this pitch.
  __shared__ __align__(16) ushort_t xb_n[2][256][32];  // [buf][ch][px] px-fastest
  __shared__ __align__(16) ushort_t xb_t[32][264];     // [px][ch^swz] ch-fastest
  __shared__ __align__(16) ushort_t knb[128][32];      // [Krow][px]
  __shared__ __align__(16) float red[2][32][12];       // [buf][px][wave]

  const int t = threadIdx.x;
  const int b = blockIdx.y;
  const int lane = t & 63, w = t >> 6, quad = lane >> 4, l16 = lane & 15;
  const int r8 = t >> 3;        // channel row-in-64 (0..63)
  const int px0 = 4 * (t & 7);  // owned pixel group
  // xb_t column swizzle: element (row,ch) stored at col ch ^ ((row>>2)<<3).
  // Write rows px0..px0+3 share key (t&7); read rows l16 / 16+l16 use rk0/rk1.
  const int xk  = (t & 7) << 3;
  const int rk0 = (l16 >> 2) << 3;
  const int rk1 = rk0 ^ 32;

  float bk_r[4];
#pragma unroll
  for (int r = 0; r < 4; ++r) bk_r[r] = bk[16 * w + 4 * quad + r];

  f32x4 accS[16];
#pragma unroll
  for (int ct = 0; ct < 16; ++ct) accS[ct] = (f32x4){0.f, 0.f, 0.f, 0.f};
  float ksump[4] = {0.f, 0.f, 0.f, 0.f};
  float xs_p[4] = {0.f, 0.f, 0.f, 0.f};
  float k0v[4], k1v[4];  // K values carried across the barrier (PhaseB_i -> PhaseA_{i+1})

  const float* xg = x + ((size_t)(b * kC) + r8) * kN + blockIdx.x * 256 + px0;

  float4 bufA[4], bufB[4];
#pragma unroll
  for (int p = 0; p < 4; ++p)
    bufA[p] = *(const float4*)(xg + (size_t)p * 64 * kN);

  auto prefetch = [&](int ti, float4 (&nxt)[4]) {
#pragma unroll
    for (int p = 0; p < 4; ++p)
      nxt[p] = *(const float4*)(xg + (size_t)p * 64 * kN + ti * 32);
  };

  auto stage = [&](int ti, float4 (&cur)[4]) {
    const int tb = ti & 1;
#pragma unroll
    for (int p = 0; p < 4; ++p) {
      float4 v = cur[p];
      const int rp = 64 * p + r8;
      xs_p[p] += v.x + v.y + v.z + v.w;
      ushort_t u0 = f2bf(v.x), u1 = f2bf(v.y), u2 = f2bf(v.z), u3 = f2bf(v.w);
      uint2 pk;
      pk.x = (unsigned)u0 | ((unsigned)u1 << 16);
      pk.y = (unsigned)u2 | ((unsigned)u3 << 16);
      *(uint2*)&xb_n[tb][rp][px0] = pk;
      const int cs = rp ^ xk;  // same key for rows px0..px0+3
      xb_t[px0 + 0][cs] = u0;
      xb_t[px0 + 1][cs] = u1;
      xb_t[px0 + 2][cs] = u2;
      xb_t[px0 + 3][cs] = u3;
    }
  };

  // PhaseB: K[128x32] = Wk * x (wave w owns K rows 16w..16w+15), red write
  auto gemm1 = [&](int ti) {
    f32x4 acc1[2] = {{0.f, 0.f, 0.f, 0.f}, {0.f, 0.f, 0.f, 0.f}};
    const ushort_t* wkbase = Wkb + (16 * w + l16) * 256 + quad * 8;
#pragma unroll
    for (int ks = 0; ks < 8; ++ks) {
      short8 a = *(const short8*)(wkbase + ks * 32);
      short8 b0 = *(const short8*)&xb_t[l16][(ks * 32 + quad * 8) ^ rk0];
      short8 b1 = *(const short8*)&xb_t[16 + l16][(ks * 32 + quad * 8) ^ rk1];
      acc1[0] = MFMA16(a, b0, acc1[0]);
      acc1[1] = MFMA16(a, b1, acc1[1]);
    }
    float ssq0 = 0.f, ssq1 = 0.f;
#pragma unroll
    for (int r = 0; r < 4; ++r) {
      k0v[r] = acc1[0][r] + bk_r[r];
      k1v[r] = acc1[1][r] + bk_r[r];
      ssq0 += k0v[r] * k0v[r];
      ssq1 += k1v[r] * k1v[r];
    }
    ssq0 += __shfl_xor(ssq0, 16); ssq0 += __shfl_xor(ssq0, 32);
    ssq1 += __shfl_xor(ssq1, 16); ssq1 += __shfl_xor(ssq1, 32);
    if (quad == 0) { red[ti & 1][l16][w] = ssq0; red[ti & 1][16 + l16][w] = ssq1; }
  };

  // PhaseA: norm tile ti (reads red[ti&1]) + GEMM2: S += Kn * x^T from xb_n[ti&1]
  auto norm_gemm2 = [&](int ti) {
    const int tb = ti & 1;
    f32x4 ra = *(const f32x4*)&red[tb][l16][0];
    f32x4 rb = *(const f32x4*)&red[tb][l16][4];
    f32x4 rc = *(const f32x4*)&red[tb][16 + l16][0];
    f32x4 rd = *(const f32x4*)&red[tb][16 + l16][4];
    const float iv0 = rsqrtf(ra[0] + ra[1] + ra[2] + ra[3] + rb[0] + rb[1] + rb[2] + rb[3]);
    const float iv1 = rsqrtf(rc[0] + rc[1] + rc[2] + rc[3] + rd[0] + rd[1] + rd[2] + rd[3]);
#pragma unroll
    for (int r = 0; r < 4; ++r) {
      float kn0 = k0v[r] * iv0, kn1 = k1v[r] * iv1;
      ksump[r] += kn0 + kn1;
      knb[16 * w + 4 * quad + r][l16] = f2bf(kn0);
      knb[16 * w + 4 * quad + r][16 + l16] = f2bf(kn1);
    }
    // knb rows 16w..16w+15 are wave-private; DS pipe is in-order per wave.
    __builtin_amdgcn_s_waitcnt(0xc07f);
    short8 a2 = *(const short8*)&knb[16 * w + l16][quad * 8];
#pragma unroll
    for (int ct = 0; ct < 16; ++ct) {
      short8 b2 = *(const short8*)&xb_n[tb][ct * 16 + l16][quad * 8];
      accS[ct] = MFMA16(a2, b2, accS[ct]);
    }
  };

  // ---- prologue ----
  prefetch(1, bufB);
  stage(0, bufA);
  sync_lds();      // B2_0
  gemm1(0);

  auto iter = [&](int ti, float4 (&cur)[4], float4 (&nxt)[4], bool pf) {
    sync_lds();    // B1_ti : red[ti-1] + xb_n[ti-1] visible; xb_t free for reuse
    if (pf) prefetch(ti + 1, nxt);
    norm_gemm2(ti - 1);
    stage(ti, cur);
    sync_lds();    // B2_ti : xb_t[ti] staged by all waves
    gemm1(ti);
  };
  iter(1, bufB, bufA, true);
  iter(2, bufA, bufB, true);
  iter(3, bufB, bufA, true);
  iter(4, bufA, bufB, true);
  iter(5, bufB, bufA, true);
  iter(6, bufA, bufB, true);
  iter(7, bufB, bufA, false);
  sync_lds();      // B1_8
  norm_gemm2(7);

  // ---- flush (forward/backward alternation de-phases cross-block contention;
  //       indices stay compile-time so accS never leaves registers) ----
  float* Sb = S + (size_t)b * kM * kC;
  if ((blockIdx.x & 1) == 0) {
#pragma unroll
    for (int ct = 0; ct < 16; ++ct)
#pragma unroll
      for (int r = 0; r < 4; ++r)
        atomicAdd(&Sb[(16 * w + 4 * quad + r) * 256 + ct * 16 + l16], accS[ct][r]);
  } else {
#pragma unroll
    for (int ct = 15; ct >= 0; --ct)
#pragma unroll
      for (int r = 0; r < 4; ++r)
        atomicAdd(&Sb[(16 * w + 4 * quad + r) * 256 + ct * 16 + l16], accS[ct][r]);
  }
#pragma unroll
  for (int r = 0; r < 4; ++r) {
    float v = ksump[r];
    v += __shfl_xor(v, 1); v += __shfl_xor(v, 2);
    v += __shfl_xor(v, 4); v += __shfl_xor(v, 8);
    if (l16 == 0) atomicAdd(&Ksum[b * kM + 16 * w + 4 * quad + r], v);
  }
#pragma unroll
  for (int p = 0; p < 4; ++p) {
    float v = xs_p[p];
    v += __shfl_xor(v, 1); v += __shfl_xor(v, 2); v += __shfl_xor(v, 4);
    if ((t & 7) == 0) atomicAdd(&xsum[b * kC + 64 * p + r8], v);
  }
}

// ---------------- K2: matT = (S*Wv^T + Ksum*bv^T)^T via hi/lo bf16 MFMA ------
// grid 256 (= 8 b x 16 c-tile x 2 m-half), block 256 (4 waves).
__global__ __launch_bounds__(256, 4)
void k2_matrix(const float* __restrict__ S, const float* __restrict__ Ksum,
               const float* __restrict__ xsum, const float* __restrict__ Wv,
               const float* __restrict__ bv, ushort_t* __restrict__ matT,
               float* __restrict__ vsum) {
  const int t = threadIdx.x;
  const int lane = t & 63, w = t >> 6, quad = lane >> 4, l16 = lane & 15;
  const int bx = blockIdx.x;
  const int b = bx >> 5, ct = (bx >> 1) & 15, mt = bx & 1;
  const int c0 = ct * 16;
  const int m0 = mt * 64 + w * 16;

  const float* arow = Wv + (size_t)(c0 + l16) * 256 + quad * 8;
  const float* brow = S + ((size_t)b * kM + m0 + l16) * 256 + quad * 8;
  const bool do_vsum = (mt == 0) && (w == 0);
  const float* xsb = xsum + b * kC + quad * 8;

  f32x4 acc = (f32x4){0.f, 0.f, 0.f, 0.f};
  float vdot = 0.f;

#pragma unroll
  for (int ks = 0; ks < 8; ++ks) {
    float4 a0 = *(const float4*)(arow + ks * 32);
    float4 a1 = *(const float4*)(arow + ks * 32 + 4);
    float4 b0 = *(const float4*)(brow + ks * 32);
    float4 b1 = *(const float4*)(brow + ks * 32 + 4);
    float av[8] = {a0.x, a0.y, a0.z, a0.w, a1.x, a1.y, a1.z, a1.w};
    float bw[8] = {b0.x, b0.y, b0.z, b0.w, b1.x, b1.y, b1.z, b1.w};
    if (do_vsum) {
      float4 x0 = *(const float4*)(xsb + ks * 32);
      float4 x1 = *(const float4*)(xsb + ks * 32 + 4);
      vdot += av[0] * x0.x + av[1] * x0.y + av[2] * x0.z + av[3] * x0.w +
              av[4] * x1.x + av[5] * x1.y + av[6] * x1.z + av[7] * x1.w;
    }
    short8 ah, al, bh, bl;
#pragma unroll
    for (int i = 0; i < 8; ++i) {
      ushort_t h = f2bf(av[i]);
      ah[i] = (short)h;
      al[i] = (short)f2bf(av[i] - bf2f(h));
      ushort_t g = f2bf(bw[i]);
      bh[i] = (short)g;
      bl[i] = (short)f2bf(bw[i] - bf2f(g));
    }
    acc = MFMA16(ah, bh, acc);
    acc = MFMA16(ah, bl, acc);
    acc = MFMA16(al, bh, acc);
  }

  const float ksm = Ksum[b * kM + m0 + l16];
  float4 bv4 = *(const float4*)(bv + c0 + quad * 4);
  float bvv[4] = {bv4.x, bv4.y, bv4.z, bv4.w};
#pragma unroll
  for (int r = 0; r < 4; ++r) {
    const int c = c0 + 4 * quad + r;
    matT[((size_t)b * kC + c) * kM + m0 + l16] = f2bf(acc[r] + ksm * bvv[r]);
  }
  if (do_vsum) {
    vdot += __shfl_xor(vdot, 16);
    vdot += __shfl_xor(vdot, 32);
    if (quad == 0)
      vsum[b * kC + c0 + l16] = vdot + 16384.f * bv[c0 + l16];
  }
}

// ---------------- K3: Q-proj -> norm/tailor -> out = g*t*(vsum + matT*qn) ----
// Pipeline-skewed like K1: PhaseA_i = {prefetch, norm/tailor(i-1)+qnb write,
// stage(i)}, PhaseB_i = {Q-proj(i)+red write, out-GEMM+store(i-1)}.
// 2 barriers/tile (was 4). grid (64, 8), block 512.
__global__ __launch_bounds__(512, 4)
void k3_out(const float* __restrict__ x, const float* __restrict__ bq,
            const ushort_t* __restrict__ Wqb, const ushort_t* __restrict__ matT,
            const float* __restrict__ Ksum, const float* __restrict__ vsum,
            const float* __restrict__ gamma, float* __restrict__ out) {
  __shared__ __align__(16) ushort_t xb_t[32][264];   // [px][ch^swz]
  __shared__ __align__(16) ushort_t qnb[32][136];    // [px][m]
  __shared__ __align__(16) float red[2][32][12];
  __shared__ __align__(16) float red2[2][32][12];

  const int t = threadIdx.x;
  const int b = blockIdx.y;
  const int lane = t & 63, w = t >> 6, quad = lane >> 4, l16 = lane & 15;
  const int r8 = t >> 3;
  const int px0 = 4 * (t & 7);
  const int xk  = (t & 7) << 3;
  const int rk0 = (l16 >> 2) << 3;
  const int rk1 = rk0 ^ 32;
  const float gm = gamma[0];

  float bq_r[4], ks_r[4], vs_r[2][4];
#pragma unroll
  for (int r = 0; r < 4; ++r) {
    bq_r[r] = bq[16 * w + 4 * quad + r];
    ks_r[r] = Ksum[b * kM + 16 * w + 4 * quad + r] + 1e-6f;
  }
#pragma unroll
  for (int mi = 0; mi < 2; ++mi)
#pragma unroll
    for (int r = 0; r < 4; ++r)
      vs_r[mi][r] = vsum[b * kC + (2 * w + mi) * 16 + 4 * quad + r];

  float q0v[4], q1v[4];     // Q values carried PhaseB_i -> PhaseA_{i+1}
  float tl0, tl1;           // tailor carried PhaseA_i -> PhaseB_i

  const float* xg = x + ((size_t)(b * kC) + r8) * kN + blockIdx.x * 256 + px0;

  float4 bufA[4], bufB[4];
#pragma unroll
  for (int p = 0; p < 4; ++p)
    bufA[p] = *(const float4*)(xg + (size_t)p * 64 * kN);

  auto prefetch3 = [&](int ti, float4 (&nxt)[4]) {
#pragma unroll
    for (int p = 0; p < 4; ++p)
      nxt[p] = *(const float4*)(xg + (size_t)p * 64 * kN + ti * 32);
  };

  auto stage3 = [&](float4 (&cur)[4]) {
#pragma unroll
    for (int p = 0; p < 4; ++p) {
      float4 v = cur[p];
      const int cs = (64 * p + r8) ^ xk;
      xb_t[px0 + 0][cs] = f2bf(v.x);
      xb_t[px0 + 1][cs] = f2bf(v.y);
      xb_t[px0 + 2][cs] = f2bf(v.z);
      xb_t[px0 + 3][cs] = f2bf(v.w);
    }
  };

  auto qproj = [&](int ti) {
    f32x4 acc1[2] = {{0.f, 0.f, 0.f, 0.f}, {0.f, 0.f, 0.f, 0.f}};
    const ushort_t* wqbase = Wqb + (16 * w + l16) * 256 + quad * 8;
#pragma unroll
    for (int ks = 0; ks < 8; ++ks) {
      short8 a = *(const short8*)(wqbase + ks * 32);
      short8 b0 = *(const short8*)&xb_t[l16][(ks * 32 + quad * 8) ^ rk0];
      short8 b1 = *(const short8*)&xb_t[16 + l16][(ks * 32 + quad * 8) ^ rk1];
      acc1[0] = MFMA16(a, b0, acc1[0]);
      acc1[1] = MFMA16(a, b1, acc1[1]);
    }
    float ssq0 = 0.f, ssq1 = 0.f, dot0 = 0.f, dot1 = 0.f;
#pragma unroll
    for (int r = 0; r < 4; ++r) {
      q0v[r] = acc1[0][r] + bq_r[r];
      q1v[r] = acc1[1][r] + bq_r[r];
      ssq0 += q0v[r] * q0v[r]; ssq1 += q1v[r] * q1v[r];
      dot0 += q0v[r] * ks_r[r]; dot1 += q1v[r] * ks_r[r];
    }
    ssq0 += __shfl_xor(ssq0, 16); ssq0 += __shfl_xor(ssq0, 32);
    ssq1 += __shfl_xor(ssq1, 16); ssq1 += __shfl_xor(ssq1, 32);
    dot0 += __shfl_xor(dot0, 16); dot0 += __shfl_xor(dot0, 32);
    dot1 += __shfl_xor(dot1, 16); dot1 += __shfl_xor(dot1, 32);
    if (quad == 0) {
      red[ti & 1][l16][w] = ssq0;  red[ti & 1][16 + l16][w] = ssq1;
      red2[ti & 1][l16][w] = dot0; red2[ti & 1][16 + l16][w] = dot1;
    }
  };

  auto normq = [&](int ti) {
    const int tb = ti & 1;
    f32x4 ra = *(const f32x4*)&red[tb][l16][0];
    f32x4 rb = *(const f32x4*)&red[tb][l16][4];
    f32x4 rc = *(const f32x4*)&red[tb][16 + l16][0];
    f32x4 rd = *(const f32x4*)&red[tb][16 + l16][4];
    f32x4 da = *(const f32x4*)&red2[tb][l16][0];
    f32x4 db = *(const f32x4*)&red2[tb][l16][4];
    f32x4 dc = *(const f32x4*)&red2[tb][16 + l16][0];
    f32x4 dd = *(const f32x4*)&red2[tb][16 + l16][4];
    const float iv0 = rsqrtf(ra[0] + ra[1] + ra[2] + ra[3] + rb[0] + rb[1] + rb[2] + rb[3]);
    const float iv1 = rsqrtf(rc[0] + rc[1] + rc[2] + rc[3] + rd[0] + rd[1] + rd[2] + rd[3]);
    const float d0 = da[0] + da[1] + da[2] + da[3] + db[0] + db[1] + db[2] + db[3];
    const float d1 = dc[0] + dc[1] + dc[2] + dc[3] + dd[0] + dd[1] + dd[2] + dd[3];
    tl0 = 1.f / (16384.f + d0 * iv0);
    tl1 = 1.f / (16384.f + d1 * iv1);
    ushort_t q0b[4], q1b[4];
#pragma unroll
    for (int r = 0; r < 4; ++r) {
      q0b[r] = f2bf(q0v[r] * iv0);
      q1b[r] = f2bf(q1v[r] * iv1);
    }
    uint2 p0, p1;
    p0.x = (unsigned)q0b[0] | ((unsigned)q0b[1] << 16);
    p0.y = (unsigned)q0b[2] | ((unsigned)q0b[3] << 16);
    p1.x = (unsigned)q1b[0] | ((unsigned)q1b[1] << 16);
    p1.y = (unsigned)q1b[2] | ((unsigned)q1b[3] << 16);
    *(uint2*)&qnb[l16][16 * w + 4 * quad] = p0;
    *(uint2*)&qnb[16 + l16][16 * w + 4 * quad] = p1;
  };

  auto outg = [&](int ti) {
    const int n0 = blockIdx.x * 256 + ti * 32;
    f32x4 accO[2][2];
#pragma unroll
    for (int mi = 0; mi < 2; ++mi)
#pragma unroll
      for (int nt = 0; nt < 2; ++nt) accO[mi][nt] = (f32x4){0.f, 0.f, 0.f, 0.f};
    const ushort_t* mrow0 = matT + ((size_t)b * kC + (2 * w) * 16 + l16) * kM + quad * 8;
    const ushort_t* mrow1 = mrow0 + 16 * kM;
#pragma unroll
    for (int ks = 0; ks < 4; ++ks) {
      short8 b0 = *(const short8*)&qnb[l16][ks * 32 + quad * 8];
      short8 b1 = *(const short8*)&qnb[16 + l16][ks * 32 + quad * 8];
      short8 a0 = *(const short8*)(mrow0 + ks * 32);
      short8 a1 = *(const short8*)(mrow1 + ks * 32);
      accO[0][0] = MFMA16(a0, b0, accO[0][0]);
      accO[0][1] = MFMA16(a0, b1, accO[0][1]);
      accO[1][0] = MFMA16(a1, b0, accO[1][0]);
      accO[1][1] = MFMA16(a1, b1, accO[1][1]);
    }
#pragma unroll
    for (int mi = 0; mi < 2; ++mi) {
#pragma unroll
      for (int r = 0; r < 4; ++r) {
        const int c = (2 * w + mi) * 16 + 4 * quad + r;
        size_t base = ((size_t)(b * kC + c)) * kN + n0;
        out[base + l16] = gm * tl0 * (vs_r[mi][r] + accO[mi][0][r]);
        out[base + 16 + l16] = gm * tl1 * (vs_r[mi][r] + accO[mi][1][r]);
      }
    }
  };

  // ---- prologue ----
  prefetch3(1, bufB);
  stage3(bufA);
  sync_lds();      // B2_0
  qproj(0);

  auto iter3 = [&](int ti, float4 (&cur)[4], float4 (&nxt)[4], bool pf) {
    sync_lds();    // B1_ti : red/red2[ti-1] visible; xb_t + qnb free for reuse
    if (pf) prefetch3(ti + 1, nxt);
    normq(ti - 1);
    stage3(cur);
    sync_lds();    // B2_ti : xb_t[ti] staged, qnb[ti-1] written by all waves
    qproj(ti);
    outg(ti - 1);
  };
  iter3(1, bufB, bufA, true);
  iter3(2, bufA, bufB, true);
  iter3(3, bufB, bufA, true);
  iter3(4, bufA, bufB, true);
  iter3(5, bufB, bufA, true);
  iter3(6, bufA, bufB, true);
  iter3(7, bufB, bufA, false);
  sync_lds();      // B1_8
  normq(7);
  sync_lds();      // B2_8 : qnb[7] cross-wave visible
  outg(7);
}

extern "C" void kernel_launch(void* const* d_in, const int* in_sizes, int n_in,
                              void* d_out, int out_size, void* d_ws, size_t ws_size,
                              hipStream_t stream) {
  (void)in_sizes; (void)n_in; (void)out_size; (void)ws_size;
  const float* x     = (const float*)d_in[0];
  const float* Wq    = (const float*)d_in[1];
  const float* bq    = (const float*)d_in[2];
  const float* Wk    = (const float*)d_in[3];
  const float* bk    = (const float*)d_in[4];
  const float* Wv    = (const float*)d_in[5];
  const float* bv    = (const float*)d_in[6];
  const float* gamma = (const float*)d_in[7];
  float* out = (float*)d_out;

  char* wsb = (char*)d_ws;
  float*    S    = (float*)(wsb + kOffS);
  float*    Ksum = (float*)(wsb + kOffKsum);
  float*    xsum = (float*)(wsb + kOffXsum);
  float*    vsum = (float*)(wsb + kOffVsum);
  ushort_t* Wkb  = (ushort_t*)(wsb + kOffWkb);
  ushort_t* Wqb  = (ushort_t*)(wsb + kOffWqb);
  ushort_t* matT = (ushort_t*)(wsb + kOffMatT);

  k0_init<<<1024, 256, 0, stream>>>(Wq, Wk, (float*)wsb, Wkb, Wqb);
  k1_acc<<<dim3(64, 8), 512, 0, stream>>>(x, bk, Wkb, S, Ksum, xsum);
  k2_matrix<<<256, 256, 0, stream>>>(S, Ksum, xsum, Wv, bv, matT, vsum);
  k3_out<<<dim3(64, 8), 512, 0, stream>>>(x, bq, Wqb, matT, Ksum, vsum, gamma, out);
}

// Round 2
// 415.105 us; speedup vs baseline: 1.2243x; 1.2243x over previous
//
#include <hip/hip_runtime.h>
#include <math.h>

typedef unsigned short ushort_t;
typedef __attribute__((ext_vector_type(4))) float f32x4;
typedef __attribute__((ext_vector_type(8))) short short8;

#define MFMA16(a, b, c) __builtin_amdgcn_mfma_f32_16x16x32_bf16((a), (b), (c), 0, 0, 0)

// Problem dims (fixed)
constexpr int kB = 8;
constexpr int kC = 256;
constexpr int kM = 128;
constexpr int kN = 16384;

// ws layout (bytes, all 256-aligned). Total ~1.65 MB.
constexpr size_t kOffS    = 0;         // fp32 [8][128][256]
constexpr size_t kOffKsum = 1048576;   // fp32 [8][128]
constexpr size_t kOffXsum = 1052672;   // fp32 [8][256]
constexpr size_t kOffVsum = 1060864;   // fp32 [8][256]
constexpr size_t kOffWkb  = 1069056;   // bf16 [128][256]
constexpr size_t kOffWqb  = 1134592;   // bf16 [128][256]
constexpr size_t kOffMatT = 1200128;   // bf16 [8][256][128]  (matrix transposed)

__device__ __forceinline__ ushort_t f2bf(float f) {
  union { float f; unsigned u; } v; v.f = f;
  unsigned r = v.u + 0x7fffu + ((v.u >> 16) & 1u);
  return (ushort_t)(r >> 16);
}
__device__ __forceinline__ float bf2f(ushort_t h) {
  union { float f; unsigned u; } v; v.u = ((unsigned)h) << 16;
  return v.f;
}

// Barrier that drains LDS only (lgkmcnt(0)) and leaves global loads in
// flight — prefetched staging loads stay outstanding across the barrier.
__device__ __forceinline__ void sync_lds() {
  __atomic_signal_fence(__ATOMIC_SEQ_CST);
  __builtin_amdgcn_s_waitcnt(0xc07f);  // lgkmcnt(0), vmcnt/expcnt untouched
  __builtin_amdgcn_s_barrier();
  __atomic_signal_fence(__ATOMIC_SEQ_CST);
}

// ---------------- K0: zero accumulators + cast weights to bf16 ---------------
__global__ void k0_init(const float* __restrict__ Wq, const float* __restrict__ Wk,
                        float* __restrict__ ws_f, ushort_t* __restrict__ Wkb,
                        ushort_t* __restrict__ Wqb) {
  int i = blockIdx.x * 256 + threadIdx.x;  // 1024 x 256 = 262144 threads
  // zero S (262144 f) + Ksum (1024 f) + xsum (2048 f) contiguous
  for (int j = i; j < 265216; j += 262144) ws_f[j] = 0.0f;
  if (i < kM * kC) {
    Wkb[i] = f2bf(Wk[i]);
    Wqb[i] = f2bf(Wq[i]);
  }
}

// ---------------- K1: K-proj (MFMA) -> L2-norm -> S += Kn * x^T (MFMA) -------
// Pipeline-skewed: PhaseA_i = {prefetch i+1, norm+GEMM2 of tile i-1, stage i},
// PhaseB_i = {GEMM1 of tile i, red write}. 2 barriers/tile.
// grid (64, 8), block 512. launch_bounds (512,2): proven 104-VGPR regime;
// (512,4) made the allocator spill accS to scratch (r1: VGPR=64, 4.5x traffic).
__global__ __launch_bounds__(512, 2)
void k1_acc(const float* __restrict__ x, const float* __restrict__ bk,
            const ushort_t* __restrict__ Wkb, float* __restrict__ S,
            float* __restrict__ Ksum, float* __restrict__ xsum) {
  // xb_n pitch 32: b128 reads land 8 dwords/bank (optimal), uint2 writes 4/bank
  // (= min for 512B). xb_t pitch 256 + 3-bit XOR key K(px)=(px>>1)&7 on col
  // bits 3-5: reads 8/bank (optimal), writes 2/bank (free). knb pitch 40:
  // writes 2/bank, reads 8/bank. red pitch 8 floats (8 waves), broadcast reads.
  __shared__ __align__(16) ushort_t xb_n[2][256][32];  // [buf][ch][px] px-fastest
  __shared__ __align__(16) ushort_t xb_t[32][256];     // [px][ch ^ key<<3]
  __shared__ __align__(16) ushort_t knb[128][40];      // [Krow][px]
  __shared__ __align__(16) float red[2][32][8];        // [buf][px][wave]

  const int t = threadIdx.x;
  const int b = blockIdx.y;
  const int lane = t & 63, w = t >> 6, quad = lane >> 4, l16 = lane & 15;
  const int r8 = t >> 3;        // channel row-in-64 (0..63)
  const int px0 = 4 * (t & 7);  // owned pixel group
  // xb_t swizzle keys. Writes: px0..px0+1 use key01, px0+2..+3 use key23.
  // Reads: rows l16 and 16+l16 share rk = ((l16>>1)&7)<<3.
  const int key01 = ((px0 >> 1) & 7) << 3;
  const int key23 = key01 ^ 8;
  const int rk = ((l16 >> 1) & 7) << 3;

  float bk_r[4];
#pragma unroll
  for (int r = 0; r < 4; ++r) bk_r[r] = bk[16 * w + 4 * quad + r];

  f32x4 accS[16];
#pragma unroll
  for (int ct = 0; ct < 16; ++ct) accS[ct] = (f32x4){0.f, 0.f, 0.f, 0.f};
  float ksump[4] = {0.f, 0.f, 0.f, 0.f};
  float xs_p[4] = {0.f, 0.f, 0.f, 0.f};
  float k0v[4], k1v[4];  // K values carried across the barrier (PhaseB_i -> PhaseA_{i+1})

  const float* xg = x + ((size_t)(b * kC) + r8) * kN + blockIdx.x * 256 + px0;

  float4 bufA[4], bufB[4];
#pragma unroll
  for (int p = 0; p < 4; ++p)
    bufA[p] = *(const float4*)(xg + (size_t)p * 64 * kN);

  auto prefetch = [&](int ti, float4 (&nxt)[4]) {
#pragma unroll
    for (int p = 0; p < 4; ++p)
      nxt[p] = *(const float4*)(xg + (size_t)p * 64 * kN + ti * 32);
  };

  auto stage = [&](int ti, float4 (&cur)[4]) {
    const int tb = ti & 1;
#pragma unroll
    for (int p = 0; p < 4; ++p) {
      float4 v = cur[p];
      const int rp = 64 * p + r8;
      xs_p[p] += v.x + v.y + v.z + v.w;
      ushort_t u0 = f2bf(v.x), u1 = f2bf(v.y), u2 = f2bf(v.z), u3 = f2bf(v.w);
      uint2 pk;
      pk.x = (unsigned)u0 | ((unsigned)u1 << 16);
      pk.y = (unsigned)u2 | ((unsigned)u3 << 16);
      *(uint2*)&xb_n[tb][rp][px0] = pk;
      xb_t[px0 + 0][rp ^ key01] = u0;
      xb_t[px0 + 1][rp ^ key01] = u1;
      xb_t[px0 + 2][rp ^ key23] = u2;
      xb_t[px0 + 3][rp ^ key23] = u3;
    }
  };

  // PhaseB: K[128x32] = Wk * x (wave w owns K rows 16w..16w+15), red write
  auto gemm1 = [&](int ti) {
    f32x4 acc1[2] = {{0.f, 0.f, 0.f, 0.f}, {0.f, 0.f, 0.f, 0.f}};
    const ushort_t* wkbase = Wkb + (16 * w + l16) * 256 + quad * 8;
#pragma unroll
    for (int ks = 0; ks < 8; ++ks) {
      short8 a = *(const short8*)(wkbase + ks * 32);
      short8 b0 = *(const short8*)&xb_t[l16][(ks * 32 + quad * 8) ^ rk];
      short8 b1 = *(const short8*)&xb_t[16 + l16][(ks * 32 + quad * 8) ^ rk];
      acc1[0] = MFMA16(a, b0, acc1[0]);
      acc1[1] = MFMA16(a, b1, acc1[1]);
    }
    float ssq0 = 0.f, ssq1 = 0.f;
#pragma unroll
    for (int r = 0; r < 4; ++r) {
      k0v[r] = acc1[0][r] + bk_r[r];
      k1v[r] = acc1[1][r] + bk_r[r];
      ssq0 += k0v[r] * k0v[r];
      ssq1 += k1v[r] * k1v[r];
    }
    ssq0 += __shfl_xor(ssq0, 16); ssq0 += __shfl_xor(ssq0, 32);
    ssq1 += __shfl_xor(ssq1, 16); ssq1 += __shfl_xor(ssq1, 32);
    if (quad == 0) { red[ti & 1][l16][w] = ssq0; red[ti & 1][16 + l16][w] = ssq1; }
  };

  // PhaseA: norm tile ti (reads red[ti&1]) + GEMM2: S += Kn * x^T from xb_n[ti&1]
  auto norm_gemm2 = [&](int ti) {
    const int tb = ti & 1;
    f32x4 ra = *(const f32x4*)&red[tb][l16][0];
    f32x4 rb = *(const f32x4*)&red[tb][l16][4];
    f32x4 rc = *(const f32x4*)&red[tb][16 + l16][0];
    f32x4 rd = *(const f32x4*)&red[tb][16 + l16][4];
    const float iv0 = rsqrtf(ra[0] + ra[1] + ra[2] + ra[3] + rb[0] + rb[1] + rb[2] + rb[3]);
    const float iv1 = rsqrtf(rc[0] + rc[1] + rc[2] + rc[3] + rd[0] + rd[1] + rd[2] + rd[3]);
#pragma unroll
    for (int r = 0; r < 4; ++r) {
      float kn0 = k0v[r] * iv0, kn1 = k1v[r] * iv1;
      ksump[r] += kn0 + kn1;
      knb[16 * w + 4 * quad + r][l16] = f2bf(kn0);
      knb[16 * w + 4 * quad + r][16 + l16] = f2bf(kn1);
    }
    // knb rows 16w..16w+15 are wave-private; DS pipe is in-order per wave.
    __builtin_amdgcn_s_waitcnt(0xc07f);
    short8 a2 = *(const short8*)&knb[16 * w + l16][quad * 8];
#pragma unroll
    for (int ct = 0; ct < 16; ++ct) {
      short8 b2 = *(const short8*)&xb_n[tb][ct * 16 + l16][quad * 8];
      accS[ct] = MFMA16(a2, b2, accS[ct]);
    }
  };

  // ---- prologue ----
  prefetch(1, bufB);
  stage(0, bufA);
  sync_lds();      // B2_0
  gemm1(0);

  auto iter = [&](int ti, float4 (&cur)[4], float4 (&nxt)[4], bool pf) {
    sync_lds();    // B1_ti : red[ti-1] + xb_n[ti-1] visible; xb_t free for reuse
    if (pf) prefetch(ti + 1, nxt);
    norm_gemm2(ti - 1);
    stage(ti, cur);
    sync_lds();    // B2_ti : xb_t[ti] staged by all waves
    gemm1(ti);
  };
  iter(1, bufB, bufA, true);
  iter(2, bufA, bufB, true);
  iter(3, bufB, bufA, true);
  iter(4, bufA, bufB, true);
  iter(5, bufB, bufA, true);
  iter(6, bufA, bufB, true);
  iter(7, bufB, bufA, false);
  sync_lds();      // B1_8
  norm_gemm2(7);

  // ---- flush (forward/backward alternation de-phases cross-block contention;
  //       indices stay compile-time so accS never leaves registers) ----
  float* Sb = S + (size_t)b * kM * kC;
  if ((blockIdx.x & 1) == 0) {
#pragma unroll
    for (int ct = 0; ct < 16; ++ct)
#pragma unroll
      for (int r = 0; r < 4; ++r)
        atomicAdd(&Sb[(16 * w + 4 * quad + r) * 256 + ct * 16 + l16], accS[ct][r]);
  } else {
#pragma unroll
    for (int ct = 15; ct >= 0; --ct)
#pragma unroll
      for (int r = 0; r < 4; ++r)
        atomicAdd(&Sb[(16 * w + 4 * quad + r) * 256 + ct * 16 + l16], accS[ct][r]);
  }
#pragma unroll
  for (int r = 0; r < 4; ++r) {
    float v = ksump[r];
    v += __shfl_xor(v, 1); v += __shfl_xor(v, 2);
    v += __shfl_xor(v, 4); v += __shfl_xor(v, 8);
    if (l16 == 0) atomicAdd(&Ksum[b * kM + 16 * w + 4 * quad + r], v);
  }
#pragma unroll
  for (int p = 0; p < 4; ++p) {
    float v = xs_p[p];
    v += __shfl_xor(v, 1); v += __shfl_xor(v, 2); v += __shfl_xor(v, 4);
    if ((t & 7) == 0) atomicAdd(&xsum[b * kC + 64 * p + r8], v);
  }
}

// ---------------- K2: matT = (S*Wv^T + Ksum*bv^T)^T via hi/lo bf16 MFMA ------
// grid 256 (= 8 b x 16 c-tile x 2 m-half), block 256 (4 waves).
__global__ __launch_bounds__(256, 4)
void k2_matrix(const float* __restrict__ S, const float* __restrict__ Ksum,
               const float* __restrict__ xsum, const float* __restrict__ Wv,
               const float* __restrict__ bv, ushort_t* __restrict__ matT,
               float* __restrict__ vsum) {
  const int t = threadIdx.x;
  const int lane = t & 63, w = t >> 6, quad = lane >> 4, l16 = lane & 15;
  const int bx = blockIdx.x;
  const int b = bx >> 5, ct = (bx >> 1) & 15, mt = bx & 1;
  const int c0 = ct * 16;
  const int m0 = mt * 64 + w * 16;

  const float* arow = Wv + (size_t)(c0 + l16) * 256 + quad * 8;
  const float* brow = S + ((size_t)b * kM + m0 + l16) * 256 + quad * 8;
  const bool do_vsum = (mt == 0) && (w == 0);
  const float* xsb = xsum + b * kC + quad * 8;

  f32x4 acc = (f32x4){0.f, 0.f, 0.f, 0.f};
  float vdot = 0.f;

#pragma unroll
  for (int ks = 0; ks < 8; ++ks) {
    float4 a0 = *(const float4*)(arow + ks * 32);
    float4 a1 = *(const float4*)(arow + ks * 32 + 4);
    float4 b0 = *(const float4*)(brow + ks * 32);
    float4 b1 = *(const float4*)(brow + ks * 32 + 4);
    float av[8] = {a0.x, a0.y, a0.z, a0.w, a1.x, a1.y, a1.z, a1.w};
    float bw[8] = {b0.x, b0.y, b0.z, b0.w, b1.x, b1.y, b1.z, b1.w};
    if (do_vsum) {
      float4 x0 = *(const float4*)(xsb + ks * 32);
      float4 x1 = *(const float4*)(xsb + ks * 32 + 4);
      vdot += av[0] * x0.x + av[1] * x0.y + av[2] * x0.z + av[3] * x0.w +
              av[4] * x1.x + av[5] * x1.y + av[6] * x1.z + av[7] * x1.w;
    }
    short8 ah, al, bh, bl;
#pragma unroll
    for (int i = 0; i < 8; ++i) {
      ushort_t h = f2bf(av[i]);
      ah[i] = (short)h;
      al[i] = (short)f2bf(av[i] - bf2f(h));
      ushort_t g = f2bf(bw[i]);
      bh[i] = (short)g;
      bl[i] = (short)f2bf(bw[i] - bf2f(g));
    }
    acc = MFMA16(ah, bh, acc);
    acc = MFMA16(ah, bl, acc);
    acc = MFMA16(al, bh, acc);
  }

  const float ksm = Ksum[b * kM + m0 + l16];
  float4 bv4 = *(const float4*)(bv + c0 + quad * 4);
  float bvv[4] = {bv4.x, bv4.y, bv4.z, bv4.w};
#pragma unroll
  for (int r = 0; r < 4; ++r) {
    const int c = c0 + 4 * quad + r;
    matT[((size_t)b * kC + c) * kM + m0 + l16] = f2bf(acc[r] + ksm * bvv[r]);
  }
  if (do_vsum) {
    vdot += __shfl_xor(vdot, 16);
    vdot += __shfl_xor(vdot, 32);
    if (quad == 0)
      vsum[b * kC + c0 + l16] = vdot + 16384.f * bv[c0 + l16];
  }
}

// ---------------- K3: Q-proj -> norm/tailor -> out = g*t*(vsum + matT*qn) ----
// Pipeline-skewed like K1: PhaseA_i = {prefetch, norm/tailor(i-1)+qnb write,
// stage(i)}, PhaseB_i = {Q-proj(i)+red write, out-GEMM+store(i-1)}.
// 2 barriers/tile. grid (64, 8), block 512.
__global__ __launch_bounds__(512, 2)
void k3_out(const float* __restrict__ x, const float* __restrict__ bq,
            const ushort_t* __restrict__ Wqb, const ushort_t* __restrict__ matT,
            const float* __restrict__ Ksum, const float* __restrict__ vsum,
            const float* __restrict__ gamma, float* __restrict__ out) {
  __shared__ __align__(16) ushort_t xb_t[32][256];   // [px][ch ^ key<<3]
  __shared__ __align__(16) ushort_t qnb[32][136];    // [px][m]
  __shared__ __align__(16) float red[2][32][8];
  __shared__ __align__(16) float red2[2][32][8];

  const int t = threadIdx.x;
  const int b = blockIdx.y;
  const int lane = t & 63, w = t >> 6, quad = lane >> 4, l16 = lane & 15;
  const int r8 = t >> 3;
  const int px0 = 4 * (t & 7);
  const int key01 = ((px0 >> 1) & 7) << 3;
  const int key23 = key01 ^ 8;
  const int rk = ((l16 >> 1) & 7) << 3;
  const float gm = gamma[0];

  float bq_r[4], ks_r[4], vs_r[2][4];
#pragma unroll
  for (int r = 0; r < 4; ++r) {
    bq_r[r] = bq[16 * w + 4 * quad + r];
    ks_r[r] = Ksum[b * kM + 16 * w + 4 * quad + r] + 1e-6f;
  }
#pragma unroll
  for (int mi = 0; mi < 2; ++mi)
#pragma unroll
    for (int r = 0; r < 4; ++r)
      vs_r[mi][r] = vsum[b * kC + (2 * w + mi) * 16 + 4 * quad + r];

  float q0v[4], q1v[4];     // Q values carried PhaseB_i -> PhaseA_{i+1}
  float tl0, tl1;           // tailor carried PhaseA_i -> PhaseB_i

  const float* xg = x + ((size_t)(b * kC) + r8) * kN + blockIdx.x * 256 + px0;

  float4 bufA[4], bufB[4];
#pragma unroll
  for (int p = 0; p < 4; ++p)
    bufA[p] = *(const float4*)(xg + (size_t)p * 64 * kN);

  auto prefetch3 = [&](int ti, float4 (&nxt)[4]) {
#pragma unroll
    for (int p = 0; p < 4; ++p)
      nxt[p] = *(const float4*)(xg + (size_t)p * 64 * kN + ti * 32);
  };

  auto stage3 = [&](float4 (&cur)[4]) {
#pragma unroll
    for (int p = 0; p < 4; ++p) {
      float4 v = cur[p];
      const int rp = 64 * p + r8;
      xb_t[px0 + 0][rp ^ key01] = f2bf(v.x);
      xb_t[px0 + 1][rp ^ key01] = f2bf(v.y);
      xb_t[px0 + 2][rp ^ key23] = f2bf(v.z);
      xb_t[px0 + 3][rp ^ key23] = f2bf(v.w);
    }
  };

  auto qproj = [&](int ti) {
    f32x4 acc1[2] = {{0.f, 0.f, 0.f, 0.f}, {0.f, 0.f, 0.f, 0.f}};
    const ushort_t* wqbase = Wqb + (16 * w + l16) * 256 + quad * 8;
#pragma unroll
    for (int ks = 0; ks < 8; ++ks) {
      short8 a = *(const short8*)(wqbase + ks * 32);
      short8 b0 = *(const short8*)&xb_t[l16][(ks * 32 + quad * 8) ^ rk];
      short8 b1 = *(const short8*)&xb_t[16 + l16][(ks * 32 + quad * 8) ^ rk];
      acc1[0] = MFMA16(a, b0, acc1[0]);
      acc1[1] = MFMA16(a, b1, acc1[1]);
    }
    float ssq0 = 0.f, ssq1 = 0.f, dot0 = 0.f, dot1 = 0.f;
#pragma unroll
    for (int r = 0; r < 4; ++r) {
      q0v[r] = acc1[0][r] + bq_r[r];
      q1v[r] = acc1[1][r] + bq_r[r];
      ssq0 += q0v[r] * q0v[r]; ssq1 += q1v[r] * q1v[r];
      dot0 += q0v[r] * ks_r[r]; dot1 += q1v[r] * ks_r[r];
    }
    ssq0 += __shfl_xor(ssq0, 16); ssq0 += __shfl_xor(ssq0, 32);
    ssq1 += __shfl_xor(ssq1, 16); ssq1 += __shfl_xor(ssq1, 32);
    dot0 += __shfl_xor(dot0, 16); dot0 += __shfl_xor(dot0, 32);
    dot1 += __shfl_xor(dot1, 16); dot1 += __shfl_xor(dot1, 32);
    if (quad == 0) {
      red[ti & 1][l16][w] = ssq0;  red[ti & 1][16 + l16][w] = ssq1;
      red2[ti & 1][l16][w] = dot0; red2[ti & 1][16 + l16][w] = dot1;
    }
  };

  auto normq = [&](int ti) {
    const int tb = ti & 1;
    f32x4 ra = *(const f32x4*)&red[tb][l16][0];
    f32x4 rb = *(const f32x4*)&red[tb][l16][4];
    f32x4 rc = *(const f32x4*)&red[tb][16 + l16][0];
    f32x4 rd = *(const f32x4*)&red[tb][16 + l16][4];
    f32x4 da = *(const f32x4*)&red2[tb][l16][0];
    f32x4 db = *(const f32x4*)&red2[tb][l16][4];
    f32x4 dc = *(const f32x4*)&red2[tb][16 + l16][0];
    f32x4 dd = *(const f32x4*)&red2[tb][16 + l16][4];
    const float iv0 = rsqrtf(ra[0] + ra[1] + ra[2] + ra[3] + rb[0] + rb[1] + rb[2] + rb[3]);
    const float iv1 = rsqrtf(rc[0] + rc[1] + rc[2] + rc[3] + rd[0] + rd[1] + rd[2] + rd[3]);
    const float d0 = da[0] + da[1] + da[2] + da[3] + db[0] + db[1] + db[2] + db[3];
    const float d1 = dc[0] + dc[1] + dc[2] + dc[3] + dd[0] + dd[1] + dd[2] + dd[3];
    tl0 = 1.f / (16384.f + d0 * iv0);
    tl1 = 1.f / (16384.f + d1 * iv1);
    ushort_t q0b[4], q1b[4];
#pragma unroll
    for (int r = 0; r < 4; ++r) {
      q0b[r] = f2bf(q0v[r] * iv0);
      q1b[r] = f2bf(q1v[r] * iv1);
    }
    uint2 p0, p1;
    p0.x = (unsigned)q0b[0] | ((unsigned)q0b[1] << 16);
    p0.y = (unsigned)q0b[2] | ((unsigned)q0b[3] << 16);
    p1.x = (unsigned)q1b[0] | ((unsigned)q1b[1] << 16);
    p1.y = (unsigned)q1b[2] | ((unsigned)q1b[3] << 16);
    *(uint2*)&qnb[l16][16 * w + 4 * quad] = p0;
    *(uint2*)&qnb[16 + l16][16 * w + 4 * quad] = p1;
  };

  auto outg = [&](int ti) {
    const int n0 = blockIdx.x * 256 + ti * 32;
    f32x4 accO[2][2];
#pragma unroll
    for (int mi = 0; mi < 2; ++mi)
#pragma unroll
      for (int nt = 0; nt < 2; ++nt) accO[mi][nt] = (f32x4){0.f, 0.f, 0.f, 0.f};
    const ushort_t* mrow0 = matT + ((size_t)b * kC + (2 * w) * 16 + l16) * kM + quad * 8;
    const ushort_t* mrow1 = mrow0 + 16 * kM;
#pragma unroll
    for (int ks = 0; ks < 4; ++ks) {
      short8 b0 = *(const short8*)&qnb[l16][ks * 32 + quad * 8];
      short8 b1 = *(const short8*)&qnb[16 + l16][ks * 32 + quad * 8];
      short8 a0 = *(const short8*)(mrow0 + ks * 32);
      short8 a1 = *(const short8*)(mrow1 + ks * 32);
      accO[0][0] = MFMA16(a0, b0, accO[0][0]);
      accO[0][1] = MFMA16(a0, b1, accO[0][1]);
      accO[1][0] = MFMA16(a1, b0, accO[1][0]);
      accO[1][1] = MFMA16(a1, b1, accO[1][1]);
    }
#pragma unroll
    for (int mi = 0; mi < 2; ++mi) {
#pragma unroll
      for (int r = 0; r < 4; ++r) {
        const int c = (2 * w + mi) * 16 + 4 * quad + r;
        size_t base = ((size_t)(b * kC + c)) * kN + n0;
        out[base + l16] = gm * tl0 * (vs_r[mi][r] + accO[mi][0][r]);
        out[base + 16 + l16] = gm * tl1 * (vs_r[mi][r] + accO[mi][1][r]);
      }
    }
  };

  // ---- prologue ----
  prefetch3(1, bufB);
  stage3(bufA);
  sync_lds();      // B2_0
  qproj(0);

  auto iter3 = [&](int ti, float4 (&cur)[4], float4 (&nxt)[4], bool pf) {
    sync_lds();    // B1_ti : red/red2[ti-1] visible; xb_t + qnb free for reuse
    if (pf) prefetch3(ti + 1, nxt);
    normq(ti - 1);
    stage3(cur);
    sync_lds();    // B2_ti : xb_t[ti] staged, qnb[ti-1] written by all waves
    qproj(ti);
    outg(ti - 1);
  };
  iter3(1, bufB, bufA, true);
  iter3(2, bufA, bufB, true);
  iter3(3, bufB, bufA, true);
  iter3(4, bufA, bufB, true);
  iter3(5, bufB, bufA, true);
  iter3(6, bufA, bufB, true);
  iter3(7, bufB, bufA, false);
  sync_lds();      // B1_8
  normq(7);
  sync_lds();      // B2_8 : qnb[7] cross-wave visible
  outg(7);
}

extern "C" void kernel_launch(void* const* d_in, const int* in_sizes, int n_in,
                              void* d_out, int out_size, void* d_ws, size_t ws_size,
                              hipStream_t stream) {
  (void)in_sizes; (void)n_in; (void)out_size; (void)ws_size;
  const float* x     = (const float*)d_in[0];
  const float* Wq    = (const float*)d_in[1];
  const float* bq    = (const float*)d_in[2];
  const float* Wk    = (const float*)d_in[3];
  const float* bk    = (const float*)d_in[4];
  const float* Wv    = (const float*)d_in[5];
  const float* bv    = (const float*)d_in[6];
  const float* gamma = (const float*)d_in[7];
  float* out = (float*)d_out;

  char* wsb = (char*)d_ws;
  float*    S    = (float*)(wsb + kOffS);
  float*    Ksum = (float*)(wsb + kOffKsum);
  float*    xsum = (float*)(wsb + kOffXsum);
  float*    vsum = (float*)(wsb + kOffVsum);
  ushort_t* Wkb  = (ushort_t*)(wsb + kOffWkb);
  ushort_t* Wqb  = (ushort_t*)(wsb + kOffWqb);
  ushort_t* matT = (ushort_t*)(wsb + kOffMatT);

  k0_init<<<1024, 256, 0, stream>>>(Wq, Wk, (float*)wsb, Wkb, Wqb);
  k1_acc<<<dim3(64, 8), 512, 0, stream>>>(x, bk, Wkb, S, Ksum, xsum);
  k2_matrix<<<256, 256, 0, stream>>>(S, Ksum, xsum, Wv, bv, matT, vsum);
  k3_out<<<dim3(64, 8), 512, 0, stream>>>(x, bq, Wqb, matT, Ksum, vsum, gamma, out);
}

// Round 3
// 343.339 us; speedup vs baseline: 1.4803x; 1.2090x over previous
//
#include <hip/hip_runtime.h>
#include <math.h>

typedef unsigned short ushort_t;
typedef __attribute__((ext_vector_type(4))) float f32x4;
typedef __attribute__((ext_vector_type(8))) short short8;

#define MFMA16(a, b, c) __builtin_amdgcn_mfma_f32_16x16x32_bf16((a), (b), (c), 0, 0, 0)

// Problem dims (fixed)
constexpr int kB = 8;
constexpr int kC = 256;
constexpr int kM = 128;
constexpr int kN = 16384;

// ws layout (bytes, 256-aligned). Total ~18.2 MB.
constexpr size_t kOffSp   = 0;          // fp32 [8][16][128][256] partial-S copies
constexpr size_t kOffS    = 16777216;   // fp32 [8][128][256]
constexpr size_t kOffKsum = 17825792;   // fp32 [8][128]
constexpr size_t kOffXsum = 17829888;   // fp32 [8][256]
constexpr size_t kOffVsum = 17838080;   // fp32 [8][256]
constexpr size_t kOffWkb  = 17846272;   // bf16 [128][256]
constexpr size_t kOffWqb  = 17911808;   // bf16 [128][256]
constexpr size_t kOffMatT = 17977344;   // bf16 [8][256][128]  (matrix transposed)

__device__ __forceinline__ ushort_t f2bf(float f) {
  union { float f; unsigned u; } v; v.f = f;
  unsigned r = v.u + 0x7fffu + ((v.u >> 16) & 1u);
  return (ushort_t)(r >> 16);
}
__device__ __forceinline__ float bf2f(ushort_t h) {
  union { float f; unsigned u; } v; v.u = ((unsigned)h) << 16;
  return v.f;
}

// Barrier that drains LDS only (lgkmcnt(0)) and leaves global loads in
// flight — avoids the compiler's vmcnt(0) drain at __syncthreads so the
// register-prefetched staging loads stay outstanding across the barrier.
__device__ __forceinline__ void sync_lds() {
  __atomic_signal_fence(__ATOMIC_SEQ_CST);
  __builtin_amdgcn_s_waitcnt(0xc07f);  // lgkmcnt(0), vmcnt/expcnt untouched
  __builtin_amdgcn_s_barrier();
  __atomic_signal_fence(__ATOMIC_SEQ_CST);
}

// ---------------- K0: zero accumulators + cast weights to bf16 ---------------
__global__ void k0_init(const float* __restrict__ Wq, const float* __restrict__ Wk,
                        float* __restrict__ ws_f, ushort_t* __restrict__ Wkb,
                        ushort_t* __restrict__ Wqb) {
  int i = blockIdx.x * 256 + threadIdx.x;  // 1024 x 256 = 262144 threads
  // zero Sp (4194304 f) as float4 (1048576 vec4), then Ksum+xsum (3072 f)
  float4 z = {0.f, 0.f, 0.f, 0.f};
  float4* sp4 = (float4*)ws_f;
#pragma unroll
  for (int j = 0; j < 4; ++j) sp4[i + j * 262144] = z;
  if (i < 3072) ws_f[4456448 + i] = 0.0f;   // Ksum (1024) + xsum (2048)
  if (i < kM * kC) {
    Wkb[i] = f2bf(Wk[i]);
    Wqb[i] = f2bf(Wq[i]);
  }
}

// ---------------- K1: K-proj (MFMA) -> L2-norm -> Sp += Kn * x^T (MFMA) ------
// grid (64, 8), block 512. Round-0 structure (proven 104-VGPR, no spill).
// Each batch has 16 S-copies; copy = blockIdx.x & 15 so only 4 blocks
// (spaced 16 apart) contend per copy -> 16x less cross-XCD line bouncing.
__global__ __launch_bounds__(512, 2)
void k1_acc(const float* __restrict__ x, const float* __restrict__ bk,
            const ushort_t* __restrict__ Wkb, float* __restrict__ Sp,
            float* __restrict__ Ksum, float* __restrict__ xsum) {
  // xb_n pitch 40: b128 reads uniform 8 dwords/bank (optimal), uint2 writes
  // 4/bank (min for 512B). xb_t pitch 256 + XOR key ((row>>1)&7)<<3 on col
  // bits 3-5: reads uniform 8/bank, writes 2/bank (free; was 8-way unswizzled
  // = the bulk of round-0's 8.06M conflict cycles). knb pitch 40: writes
  // 2/bank, reads 8/bank.
  __shared__ __align__(16) ushort_t xb_n[256][40];   // [ch][px]  (px-fastest)
  __shared__ __align__(16) ushort_t xb_t[32][256];   // [px][ch ^ key<<3]
  __shared__ __align__(16) ushort_t knb[128][40];    // [Krow][px]
  __shared__ __align__(16) float red[32][12];        // [px][wave]

  const int t = threadIdx.x;
  const int b = blockIdx.y;
  const int lane = t & 63, w = t >> 6, quad = lane >> 4, l16 = lane & 15;
  const int r8 = t >> 3;        // channel row-in-64 (0..63)
  const int px0 = 4 * (t & 7);  // owned pixel group
  // xb_t swizzle keys: element (row,ch) stored at col ch ^ (((row>>1)&7)<<3).
  // Writes: rows px0..px0+1 share key01, px0+2..+3 share key23 = key01^8.
  // Reads: rows l16 and 16+l16 share rk (bit3 of row>>1 is masked out).
  const int key01 = (((px0 >> 1)) & 7) << 3;
  const int key23 = key01 ^ 8;
  const int rk = ((l16 >> 1) & 7) << 3;

  float bk_r[4];
#pragma unroll
  for (int r = 0; r < 4; ++r) bk_r[r] = bk[16 * w + 4 * quad + r];

  f32x4 accS[16];
#pragma unroll
  for (int ct = 0; ct < 16; ++ct) accS[ct] = (f32x4){0.f, 0.f, 0.f, 0.f};
  float ksump[4] = {0.f, 0.f, 0.f, 0.f};
  float xs_p[4] = {0.f, 0.f, 0.f, 0.f};

  // staging base: thread covers rows r8 + 64p, pixels px0..px0+3
  const float* xg = x + ((size_t)(b * kC) + r8) * kN + blockIdx.x * 256 + px0;

  float4 bufA[4], bufB[4];
#pragma unroll
  for (int p = 0; p < 4; ++p)
    bufA[p] = *(const float4*)(xg + (size_t)p * 64 * kN);

  auto step = [&](int ti, float4 (&cur)[4], float4 (&nxt)[4]) {
    sync_lds();  // previous tile's LDS consumers done
    if (ti < 7) {
#pragma unroll
      for (int p = 0; p < 4; ++p)
        nxt[p] = *(const float4*)(xg + (size_t)p * 64 * kN + (ti + 1) * 32);
    }
#pragma unroll
    for (int p = 0; p < 4; ++p) {
      float4 v = cur[p];
      const int rp = 64 * p + r8;
      xs_p[p] += v.x + v.y + v.z + v.w;
      ushort_t u0 = f2bf(v.x), u1 = f2bf(v.y), u2 = f2bf(v.z), u3 = f2bf(v.w);
      uint2 pk;
      pk.x = (unsigned)u0 | ((unsigned)u1 << 16);
      pk.y = (unsigned)u2 | ((unsigned)u3 << 16);
      *(uint2*)&xb_n[rp][px0] = pk;
      xb_t[px0 + 0][rp ^ key01] = u0;
      xb_t[px0 + 1][rp ^ key01] = u1;
      xb_t[px0 + 2][rp ^ key23] = u2;
      xb_t[px0 + 3][rp ^ key23] = u3;
    }
    sync_lds();  // stage done

    // ---- GEMM1: K[128x32] = Wk * x (wave w owns K rows 16w..16w+15) ----
    f32x4 acc1[2] = {{0.f, 0.f, 0.f, 0.f}, {0.f, 0.f, 0.f, 0.f}};
    const ushort_t* wkbase = Wkb + (16 * w + l16) * 256 + quad * 8;
#pragma unroll
    for (int ks = 0; ks < 8; ++ks) {
      short8 a = *(const short8*)(wkbase + ks * 32);
      short8 b0 = *(const short8*)&xb_t[l16][(ks * 32 + quad * 8) ^ rk];
      short8 b1 = *(const short8*)&xb_t[16 + l16][(ks * 32 + quad * 8) ^ rk];
      acc1[0] = MFMA16(a, b0, acc1[0]);
      acc1[1] = MFMA16(a, b1, acc1[1]);
    }
    float k0v[4], k1v[4];
    float ssq0 = 0.f, ssq1 = 0.f;
#pragma unroll
    for (int r = 0; r < 4; ++r) {
      k0v[r] = acc1[0][r] + bk_r[r];
      k1v[r] = acc1[1][r] + bk_r[r];
      ssq0 += k0v[r] * k0v[r];
      ssq1 += k1v[r] * k1v[r];
    }
    ssq0 += __shfl_xor(ssq0, 16); ssq0 += __shfl_xor(ssq0, 32);
    ssq1 += __shfl_xor(ssq1, 16); ssq1 += __shfl_xor(ssq1, 32);
    if (quad == 0) { red[l16][w] = ssq0; red[16 + l16][w] = ssq1; }
    sync_lds();  // red ready

    // every lane sums the 8 wave-partials itself (no serialized pass)
    f32x4 ra = *(const f32x4*)&red[l16][0];
    f32x4 rb = *(const f32x4*)&red[l16][4];
    f32x4 rc = *(const f32x4*)&red[16 + l16][0];
    f32x4 rd = *(const f32x4*)&red[16 + l16][4];
    const float iv0 = rsqrtf(ra[0] + ra[1] + ra[2] + ra[3] + rb[0] + rb[1] + rb[2] + rb[3]);
    const float iv1 = rsqrtf(rc[0] + rc[1] + rc[2] + rc[3] + rd[0] + rd[1] + rd[2] + rd[3]);
#pragma unroll
    for (int r = 0; r < 4; ++r) {
      float kn0 = k0v[r] * iv0, kn1 = k1v[r] * iv1;
      ksump[r] += kn0 + kn1;
      knb[16 * w + 4 * quad + r][l16] = f2bf(kn0);
      knb[16 * w + 4 * quad + r][16 + l16] = f2bf(kn1);
    }
    // knb rows 16w..16w+15 are wave-private: DS pipe is in-order per wave,
    // so no barrier needed before reading them back.
    __builtin_amdgcn_s_waitcnt(0xc07f);

    // ---- GEMM2: S[128x256] += Kn * x^T (Kdim = 32 px) ----
    short8 a2 = *(const short8*)&knb[16 * w + l16][quad * 8];
#pragma unroll
    for (int ct = 0; ct < 16; ++ct) {
      short8 b2 = *(const short8*)&xb_n[ct * 16 + l16][quad * 8];
      accS[ct] = MFMA16(a2, b2, accS[ct]);
    }
  };

  for (int ti = 0; ti < 8; ti += 2) {
    step(ti, bufA, bufB);
    step(ti + 1, bufB, bufA);
  }

  // ---- flush into this block's S-copy (4 contributors each, spaced 16
  //      apart in blockIdx; bit4 alternates direction to de-phase them) ----
  float* Sb = Sp + ((size_t)(b * 16) + (blockIdx.x & 15)) * kM * kC;
  if (((blockIdx.x >> 4) & 1) == 0) {
#pragma unroll
    for (int ct = 0; ct < 16; ++ct)
#pragma unroll
      for (int r = 0; r < 4; ++r)
        atomicAdd(&Sb[(16 * w + 4 * quad + r) * 256 + ct * 16 + l16], accS[ct][r]);
  } else {
#pragma unroll
    for (int ct = 15; ct >= 0; --ct)
#pragma unroll
      for (int r = 0; r < 4; ++r)
        atomicAdd(&Sb[(16 * w + 4 * quad + r) * 256 + ct * 16 + l16], accS[ct][r]);
  }
#pragma unroll
  for (int r = 0; r < 4; ++r) {
    float v = ksump[r];
    v += __shfl_xor(v, 1); v += __shfl_xor(v, 2);
    v += __shfl_xor(v, 4); v += __shfl_xor(v, 8);
    if (l16 == 0) atomicAdd(&Ksum[b * kM + 16 * w + 4 * quad + r], v);
  }
#pragma unroll
  for (int p = 0; p < 4; ++p) {
    float v = xs_p[p];
    v += __shfl_xor(v, 1); v += __shfl_xor(v, 2); v += __shfl_xor(v, 4);
    if ((t & 7) == 0) atomicAdd(&xsum[b * kC + 64 * p + r8], v);
  }
}

// ---------------- K1R: S = sum of 16 partial copies -------------------------
// grid 1024 x 256. Coalesced: thread idx owns one S element, sums p-strided.
__global__ __launch_bounds__(256)
void k1_reduce(const float* __restrict__ Sp, float* __restrict__ S) {
  const int idx = blockIdx.x * 256 + threadIdx.x;  // 0..262143
  const int b = idx >> 15, rem = idx & 32767;
  const float* base = Sp + (((size_t)b * 16) << 15) + rem;
  float s = 0.f;
#pragma unroll
  for (int p = 0; p < 16; ++p) s += base[(size_t)p << 15];
  S[idx] = s;
}

// ---------------- K2: matT = (S*Wv^T + Ksum*bv^T)^T via hi/lo bf16 MFMA ------
// grid 256 (= 8 b x 16 c-tile x 2 m-half), block 256 (4 waves).
// hi/lo split keeps fp32-level accuracy: A*B ~= Ah*Bh + Ah*Bl + Al*Bh.
__global__ __launch_bounds__(256, 4)
void k2_matrix(const float* __restrict__ S, const float* __restrict__ Ksum,
               const float* __restrict__ xsum, const float* __restrict__ Wv,
               const float* __restrict__ bv, ushort_t* __restrict__ matT,
               float* __restrict__ vsum) {
  const int t = threadIdx.x;
  const int lane = t & 63, w = t >> 6, quad = lane >> 4, l16 = lane & 15;
  const int bx = blockIdx.x;
  const int b = bx >> 5, ct = (bx >> 1) & 15, mt = bx & 1;
  const int c0 = ct * 16;
  const int m0 = mt * 64 + w * 16;

  const float* arow = Wv + (size_t)(c0 + l16) * 256 + quad * 8;   // A: Wv rows (c)
  const float* brow = S + ((size_t)b * kM + m0 + l16) * 256 + quad * 8;  // B: S rows (m)
  const bool do_vsum = (mt == 0) && (w == 0);
  const float* xsb = xsum + b * kC + quad * 8;

  f32x4 acc = (f32x4){0.f, 0.f, 0.f, 0.f};
  float vdot = 0.f;

#pragma unroll
  for (int ks = 0; ks < 8; ++ks) {
    float4 a0 = *(const float4*)(arow + ks * 32);
    float4 a1 = *(const float4*)(arow + ks * 32 + 4);
    float4 b0 = *(const float4*)(brow + ks * 32);
    float4 b1 = *(const float4*)(brow + ks * 32 + 4);
    float av[8] = {a0.x, a0.y, a0.z, a0.w, a1.x, a1.y, a1.z, a1.w};
    float bw[8] = {b0.x, b0.y, b0.z, b0.w, b1.x, b1.y, b1.z, b1.w};
    if (do_vsum) {
      float4 x0 = *(const float4*)(xsb + ks * 32);
      float4 x1 = *(const float4*)(xsb + ks * 32 + 4);
      vdot += av[0] * x0.x + av[1] * x0.y + av[2] * x0.z + av[3] * x0.w +
              av[4] * x1.x + av[5] * x1.y + av[6] * x1.z + av[7] * x1.w;
    }
    short8 ah, al, bh, bl;
#pragma unroll
    for (int i = 0; i < 8; ++i) {
      ushort_t h = f2bf(av[i]);
      ah[i] = (short)h;
      al[i] = (short)f2bf(av[i] - bf2f(h));
      ushort_t g = f2bf(bw[i]);
      bh[i] = (short)g;
      bl[i] = (short)f2bf(bw[i] - bf2f(g));
    }
    acc = MFMA16(ah, bh, acc);
    acc = MFMA16(ah, bl, acc);
    acc = MFMA16(al, bh, acc);
  }

  const float ksm = Ksum[b * kM + m0 + l16];
  float4 bv4 = *(const float4*)(bv + c0 + quad * 4);
  float bvv[4] = {bv4.x, bv4.y, bv4.z, bv4.w};
#pragma unroll
  for (int r = 0; r < 4; ++r) {
    const int c = c0 + 4 * quad + r;
    matT[((size_t)b * kC + c) * kM + m0 + l16] = f2bf(acc[r] + ksm * bvv[r]);
  }
  if (do_vsum) {
    vdot += __shfl_xor(vdot, 16);
    vdot += __shfl_xor(vdot, 32);
    if (quad == 0)
      vsum[b * kC + c0 + l16] = vdot + 16384.f * bv[c0 + l16];
  }
}

// ---------------- K3: Q-proj -> norm/tailor -> out = g*t*(vsum + matT*qn) ----
// grid (64, 8), block 512. Round-0 structure + swizzled xb_t.
__global__ __launch_bounds__(512, 2)
void k3_out(const float* __restrict__ x, const float* __restrict__ bq,
            const ushort_t* __restrict__ Wqb, const ushort_t* __restrict__ matT,
            const float* __restrict__ Ksum, const float* __restrict__ vsum,
            const float* __restrict__ gamma, float* __restrict__ out) {
  __shared__ __align__(16) ushort_t xb_t[32][256];   // [px][ch ^ key<<3]
  __shared__ __align__(16) ushort_t qnb[32][136];    // [px][m]
  __shared__ __align__(16) float red[32][12];
  __shared__ __align__(16) float red2[32][12];

  const int t = threadIdx.x;
  const int b = blockIdx.y;
  const int lane = t & 63, w = t >> 6, quad = lane >> 4, l16 = lane & 15;
  const int r8 = t >> 3;
  const int px0 = 4 * (t & 7);
  const int key01 = (((px0 >> 1)) & 7) << 3;
  const int key23 = key01 ^ 8;
  const int rk = ((l16 >> 1) & 7) << 3;
  const float gm = gamma[0];

  float bq_r[4], ks_r[4], vs_r[2][4];
#pragma unroll
  for (int r = 0; r < 4; ++r) {
    bq_r[r] = bq[16 * w + 4 * quad + r];
    ks_r[r] = Ksum[b * kM + 16 * w + 4 * quad + r] + 1e-6f;
  }
#pragma unroll
  for (int mi = 0; mi < 2; ++mi)
#pragma unroll
    for (int r = 0; r < 4; ++r)
      vs_r[mi][r] = vsum[b * kC + (2 * w + mi) * 16 + 4 * quad + r];

  const float* xg = x + ((size_t)(b * kC) + r8) * kN + blockIdx.x * 256 + px0;

  float4 bufA[4], bufB[4];
#pragma unroll
  for (int p = 0; p < 4; ++p)
    bufA[p] = *(const float4*)(xg + (size_t)p * 64 * kN);

  auto step = [&](int ti, float4 (&cur)[4], float4 (&nxt)[4]) {
    const int n0 = blockIdx.x * 256 + ti * 32;
    sync_lds();
    if (ti < 7) {
#pragma unroll
      for (int p = 0; p < 4; ++p)
        nxt[p] = *(const float4*)(xg + (size_t)p * 64 * kN + (ti + 1) * 32);
    }
#pragma unroll
    for (int p = 0; p < 4; ++p) {
      float4 v = cur[p];
      const int rp = 64 * p + r8;
      xb_t[px0 + 0][rp ^ key01] = f2bf(v.x);
      xb_t[px0 + 1][rp ^ key01] = f2bf(v.y);
      xb_t[px0 + 2][rp ^ key23] = f2bf(v.z);
      xb_t[px0 + 3][rp ^ key23] = f2bf(v.w);
    }
    sync_lds();

    // Q projection
    f32x4 acc1[2] = {{0.f, 0.f, 0.f, 0.f}, {0.f, 0.f, 0.f, 0.f}};
    const ushort_t* wqbase = Wqb + (16 * w + l16) * 256 + quad * 8;
#pragma unroll
    for (int ks = 0; ks < 8; ++ks) {
      short8 a = *(const short8*)(wqbase + ks * 32);
      short8 b0 = *(const short8*)&xb_t[l16][(ks * 32 + quad * 8) ^ rk];
      short8 b1 = *(const short8*)&xb_t[16 + l16][(ks * 32 + quad * 8) ^ rk];
      acc1[0] = MFMA16(a, b0, acc1[0]);
      acc1[1] = MFMA16(a, b1, acc1[1]);
    }
    float q0v[4], q1v[4];
    float ssq0 = 0.f, ssq1 = 0.f, dot0 = 0.f, dot1 = 0.f;
#pragma unroll
    for (int r = 0; r < 4; ++r) {
      q0v[r] = acc1[0][r] + bq_r[r];
      q1v[r] = acc1[1][r] + bq_r[r];
      ssq0 += q0v[r] * q0v[r]; ssq1 += q1v[r] * q1v[r];
      dot0 += q0v[r] * ks_r[r]; dot1 += q1v[r] * ks_r[r];
    }
    ssq0 += __shfl_xor(ssq0, 16); ssq0 += __shfl_xor(ssq0, 32);
    ssq1 += __shfl_xor(ssq1, 16); ssq1 += __shfl_xor(ssq1, 32);
    dot0 += __shfl_xor(dot0, 16); dot0 += __shfl_xor(dot0, 32);
    dot1 += __shfl_xor(dot1, 16); dot1 += __shfl_xor(dot1, 32);
    if (quad == 0) {
      red[l16][w] = ssq0;  red[16 + l16][w] = ssq1;
      red2[l16][w] = dot0; red2[16 + l16][w] = dot1;
    }
    sync_lds();
    f32x4 ra = *(const f32x4*)&red[l16][0];
    f32x4 rb = *(const f32x4*)&red[l16][4];
    f32x4 rc = *(const f32x4*)&red[16 + l16][0];
    f32x4 rd = *(const f32x4*)&red[16 + l16][4];
    f32x4 da = *(const f32x4*)&red2[l16][0];
    f32x4 db = *(const f32x4*)&red2[l16][4];
    f32x4 dc = *(const f32x4*)&red2[16 + l16][0];
    f32x4 dd = *(const f32x4*)&red2[16 + l16][4];
    const float iv0 = rsqrtf(ra[0] + ra[1] + ra[2] + ra[3] + rb[0] + rb[1] + rb[2] + rb[3]);
    const float iv1 = rsqrtf(rc[0] + rc[1] + rc[2] + rc[3] + rd[0] + rd[1] + rd[2] + rd[3]);
    const float d0 = da[0] + da[1] + da[2] + da[3] + db[0] + db[1] + db[2] + db[3];
    const float d1 = dc[0] + dc[1] + dc[2] + dc[3] + dd[0] + dd[1] + dd[2] + dd[3];
    const float tl0 = 1.f / (16384.f + d0 * iv0);
    const float tl1 = 1.f / (16384.f + d1 * iv1);
    {
      ushort_t q0b[4], q1b[4];
#pragma unroll
      for (int r = 0; r < 4; ++r) {
        q0b[r] = f2bf(q0v[r] * iv0);
        q1b[r] = f2bf(q1v[r] * iv1);
      }
      uint2 p0, p1;
      p0.x = (unsigned)q0b[0] | ((unsigned)q0b[1] << 16);
      p0.y = (unsigned)q0b[2] | ((unsigned)q0b[3] << 16);
      p1.x = (unsigned)q1b[0] | ((unsigned)q1b[1] << 16);
      p1.y = (unsigned)q1b[2] | ((unsigned)q1b[3] << 16);
      *(uint2*)&qnb[l16][16 * w + 4 * quad] = p0;
      *(uint2*)&qnb[16 + l16][16 * w + 4 * quad] = p1;
    }
    sync_lds();  // qnb is read cross-wave

    // out-GEMM: O[256 x 32] = matT * qn  (wave w owns c-tiles 2w, 2w+1)
    f32x4 accO[2][2];
#pragma unroll
    for (int mi = 0; mi < 2; ++mi)
#pragma unroll
      for (int nt = 0; nt < 2; ++nt) accO[mi][nt] = (f32x4){0.f, 0.f, 0.f, 0.f};
    const ushort_t* mrow0 = matT + ((size_t)b * kC + (2 * w) * 16 + l16) * kM + quad * 8;
    const ushort_t* mrow1 = mrow0 + 16 * kM;
#pragma unroll
    for (int ks = 0; ks < 4; ++ks) {
      short8 b0 = *(const short8*)&qnb[l16][ks * 32 + quad * 8];
      short8 b1 = *(const short8*)&qnb[16 + l16][ks * 32 + quad * 8];
      short8 a0 = *(const short8*)(mrow0 + ks * 32);
      short8 a1 = *(const short8*)(mrow1 + ks * 32);
      accO[0][0] = MFMA16(a0, b0, accO[0][0]);
      accO[0][1] = MFMA16(a0, b1, accO[0][1]);
      accO[1][0] = MFMA16(a1, b0, accO[1][0]);
      accO[1][1] = MFMA16(a1, b1, accO[1][1]);
    }
#pragma unroll
    for (int mi = 0; mi < 2; ++mi) {
#pragma unroll
      for (int r = 0; r < 4; ++r) {
        const int c = (2 * w + mi) * 16 + 4 * quad + r;
        size_t base = ((size_t)(b * kC + c)) * kN + n0;
        out[base + l16] = gm * tl0 * (vs_r[mi][r] + accO[mi][0][r]);
        out[base + 16 + l16] = gm * tl1 * (vs_r[mi][r] + accO[mi][1][r]);
      }
    }
  };

  for (int ti = 0; ti < 8; ti += 2) {
    step(ti, bufA, bufB);
    step(ti + 1, bufB, bufA);
  }
}

extern "C" void kernel_launch(void* const* d_in, const int* in_sizes, int n_in,
                              void* d_out, int out_size, void* d_ws, size_t ws_size,
                              hipStream_t stream) {
  (void)in_sizes; (void)n_in; (void)out_size; (void)ws_size;
  const float* x     = (const float*)d_in[0];
  const float* Wq    = (const float*)d_in[1];
  const float* bq    = (const float*)d_in[2];
  const float* Wk    = (const float*)d_in[3];
  const float* bk    = (const float*)d_in[4];
  const float* Wv    = (const float*)d_in[5];
  const float* bv    = (const float*)d_in[6];
  const float* gamma = (const float*)d_in[7];
  float* out = (float*)d_out;

  char* wsb = (char*)d_ws;
  float*    Sp   = (float*)(wsb + kOffSp);
  float*    S    = (float*)(wsb + kOffS);
  float*    Ksum = (float*)(wsb + kOffKsum);
  float*    xsum = (float*)(wsb + kOffXsum);
  float*    vsum = (float*)(wsb + kOffVsum);
  ushort_t* Wkb  = (ushort_t*)(wsb + kOffWkb);
  ushort_t* Wqb  = (ushort_t*)(wsb + kOffWqb);
  ushort_t* matT = (ushort_t*)(wsb + kOffMatT);

  k0_init<<<1024, 256, 0, stream>>>(Wq, Wk, (float*)wsb, Wkb, Wqb);
  k1_acc<<<dim3(64, 8), 512, 0, stream>>>(x, bk, Wkb, Sp, Ksum, xsum);
  k1_reduce<<<1024, 256, 0, stream>>>(Sp, S);
  k2_matrix<<<256, 256, 0, stream>>>(S, Ksum, xsum, Wv, bv, matT, vsum);
  k3_out<<<dim3(64, 8), 512, 0, stream>>>(x, bq, Wqb, matT, Ksum, vsum, gamma, out);
}